// Round 1
// baseline (9202.062 us; speedup 1.0000x reference)
//
#include <hip/hip_runtime.h>
#include <math.h>

#define BB 64
#define SS 256
#define D_IN 400
#define D_RNN 200
#define HID 256
#define G4 1024   // 4*HID

// workspace layout (float offsets)
#define OFF_WTLIN 0                          // [400][200]
#define OFF_WTIH  (OFF_WTLIN + 400*200)      // [2][200][1024]
#define OFF_WHHT  (OFF_WTIH + 2*200*1024)    // [2][256][1024]
#define OFF_X     (OFF_WHHT + 2*256*1024)    // [2][64][256][200]
#define OFF_GX    (OFF_X + 2*64*256*200)     // [2][64][256][1024]

__device__ __forceinline__ float sigm_f(float x) {
    return 1.0f / (1.0f + __expf(-x));
}
__device__ __forceinline__ float tanh_f(float x) {
    return 2.0f / (1.0f + __expf(-2.0f * x)) - 1.0f;
}

// ---------------- transposes ----------------
__global__ void kt_wlin(const float* __restrict__ W, float* __restrict__ Wt) {
    int id = blockIdx.x * 256 + threadIdx.x;
    if (id >= D_RNN * D_IN) return;
    int j = id / D_IN, k = id % D_IN;
    Wt[k * D_RNN + j] = W[id];
}

__global__ void kt_wih(const float* __restrict__ Wl, const float* __restrict__ Wr,
                       float* __restrict__ Wt) {
    int id = blockIdx.x * 256 + threadIdx.x;
    if (id >= 2 * G4 * D_RNN) return;
    int dir = id / (G4 * D_RNN);
    int r = id % (G4 * D_RNN);
    int j = r / D_RNN, k = r % D_RNN;
    const float* src = dir ? Wr : Wl;
    Wt[dir * (D_RNN * G4) + k * G4 + j] = src[r];
}

__global__ void kt_whh(const float* __restrict__ Wl, const float* __restrict__ Wr,
                       float* __restrict__ Wt) {
    int id = blockIdx.x * 256 + threadIdx.x;
    if (id >= 2 * G4 * HID) return;
    int dir = id / (G4 * HID);
    int r = id % (G4 * HID);
    int j = r / HID, k = r % HID;
    const float* src = dir ? Wr : Wl;
    Wt[dir * (HID * G4) + k * G4 + j] = src[r];
}

// ---------------- K1: embeddings + concat + linear + tanh ----------------
// 16 tokens per block, 512 threads. Produces x[2][B][S][200].
__launch_bounds__(512)
__global__ void k_embed_linear(const int* __restrict__ ci, const int* __restrict__ bli,
                               const int* __restrict__ bri, const int* __restrict__ sci,
                               const int* __restrict__ sbli, const int* __restrict__ sbri,
                               const float* __restrict__ ce, const float* __restrict__ be,
                               const float* __restrict__ sce, const float* __restrict__ sbe,
                               const float* __restrict__ Wt, const float* __restrict__ blin,
                               float* __restrict__ xout) {
    __shared__ __align__(16) float vec[16][2][D_IN];   // 51.2 KB
    __shared__ int idx[16][6];
    int tid = threadIdx.x;
    int g0 = blockIdx.x * 16;

    if (tid < 96) {
        int tt = tid / 6, w = tid % 6;
        int g = g0 + tt;
        const int* arr = (w == 0) ? ci : (w == 1) ? sci : (w == 2) ? bli
                         : (w == 3) ? bri : (w == 4) ? sbli : sbri;
        idx[tt][w] = arr[g];
    }
    __syncthreads();

    for (int v = tid; v < 16 * D_IN; v += 512) {
        int tt = v / D_IN, p = v % D_IN;
        float lv, rv;
        if (p < 100)      { float e = ce[idx[tt][0] * 100 + p];        lv = rv = e; }
        else if (p < 200) { float e = sce[idx[tt][1] * 100 + (p - 100)]; lv = rv = e; }
        else if (p < 300) { int q = p - 200;
                            lv = be[idx[tt][2] * 100 + q];
                            rv = be[idx[tt][3] * 100 + q]; }
        else              { int q = p - 300;
                            lv = sbe[idx[tt][4] * 100 + q];
                            rv = sbe[idx[tt][5] * 100 + q]; }
        vec[tt][0][p] = lv;
        vec[tt][1][p] = rv;
    }
    __syncthreads();

    if (tid < 400) {
        int side = tid / 200, j = tid % 200;
        float acc[16];
        #pragma unroll
        for (int t = 0; t < 16; t++) acc[t] = 0.0f;

        for (int k4 = 0; k4 < D_IN / 4; k4++) {
            float w0 = Wt[(4 * k4 + 0) * D_RNN + j];
            float w1 = Wt[(4 * k4 + 1) * D_RNN + j];
            float w2 = Wt[(4 * k4 + 2) * D_RNN + j];
            float w3 = Wt[(4 * k4 + 3) * D_RNN + j];
            #pragma unroll
            for (int t = 0; t < 16; t++) {
                float4 xv = *(const float4*)&vec[t][side][4 * k4];
                acc[t] += xv.x * w0 + xv.y * w1 + xv.z * w2 + xv.w * w3;
            }
        }
        float bias = blin[j];
        #pragma unroll
        for (int t = 0; t < 16; t++) {
            int g = g0 + t;
            int b = g >> 8, s = g & 255;
            xout[((side * BB + b) * SS + s) * D_RNN + j] = tanh_f(acc[t] + bias);
        }
    }
}

// ---------------- K2: gate-x GEMM ----------------
// 32 tokens (one dir) per block, 512 threads. gx = x @ Wih^T + (bih+bhh).
__launch_bounds__(512)
__global__ void k_gatex(const float* __restrict__ x, const float* __restrict__ WtIh,
                        const float* __restrict__ bihl, const float* __restrict__ bhhl,
                        const float* __restrict__ bihr, const float* __restrict__ bhhr,
                        float* __restrict__ gx) {
    __shared__ __align__(16) float xT[D_RNN][36];   // padded: 28.8 KB
    int tid = threadIdx.x;
    int id = blockIdx.x;            // 1024 blocks
    int dir = id >> 9;
    int rem = id & 511;
    int b = rem >> 3;
    int s0 = (rem & 7) * 32;

    const float* xbase = x + ((dir * BB + b) * SS + s0) * D_RNN;
    for (int v = tid; v < 32 * D_RNN; v += 512) {
        int tt = v / D_RNN, k = v % D_RNN;
        xT[k][tt] = xbase[tt * D_RNN + k];
    }
    __syncthreads();

    const float* Wp = WtIh + dir * (D_RNN * G4);
    int j0 = tid, j1 = tid + 512;
    float acc0[32], acc1[32];
    #pragma unroll
    for (int t = 0; t < 32; t++) { acc0[t] = 0.0f; acc1[t] = 0.0f; }

    for (int k = 0; k < D_RNN; k++) {
        float w0 = Wp[k * G4 + j0];
        float w1 = Wp[k * G4 + j1];
        #pragma unroll
        for (int m = 0; m < 8; m++) {
            float4 xv = *(const float4*)&xT[k][4 * m];
            acc0[4 * m + 0] += xv.x * w0;
            acc0[4 * m + 1] += xv.y * w0;
            acc0[4 * m + 2] += xv.z * w0;
            acc0[4 * m + 3] += xv.w * w0;
            acc1[4 * m + 0] += xv.x * w1;
            acc1[4 * m + 1] += xv.y * w1;
            acc1[4 * m + 2] += xv.z * w1;
            acc1[4 * m + 3] += xv.w * w1;
        }
    }

    float bs0, bs1;
    if (dir) { bs0 = bihr[j0] + bhhr[j0]; bs1 = bihr[j1] + bhhr[j1]; }
    else     { bs0 = bihl[j0] + bhhl[j0]; bs1 = bihl[j1] + bhhl[j1]; }

    float* gbase = gx + ((dir * BB + b) * SS + s0) * G4;
    #pragma unroll
    for (int t = 0; t < 32; t++) {
        gbase[t * G4 + j0] = acc0[t] + bs0;
        gbase[t * G4 + j1] = acc1[t] + bs1;
    }
}

// ---------------- K3: sequential LSTM, one block per (batch, dir) ----------------
// 1024 threads; thread t owns gate column t; Whh row t held in registers
// (loaded coalesced from transposed WhhT). h broadcast via LDS.
__launch_bounds__(1024, 1)
__global__ void k_lstm(const float* __restrict__ WhhT, const float* __restrict__ gx,
                       float* __restrict__ out) {
    __shared__ __align__(16) float h[HID];
    __shared__ float gates[G4];
    int t = threadIdx.x;
    int blk = blockIdx.x;          // 128
    int b = blk & 63, dir = blk >> 6;

    const float* Wp = WhhT + dir * (HID * G4) + t;
    float w[HID];
    #pragma unroll
    for (int k = 0; k < HID; k++) w[k] = Wp[k * G4];

    const float* gxp = gx + ((size_t)(dir * BB + b) * SS) * G4;
    float* outp = out + (size_t)b * SS * (2 * HID) + dir * HID;

    if (t < HID) h[t] = 0.0f;
    float c = 0.0f;
    __syncthreads();

    int s = dir ? (SS - 1) : 0;
    int ds = dir ? -1 : 1;
    float gxv = gxp[s * G4 + t];

    for (int step = 0; step < SS; step++) {
        int snext = s + ds;
        float gxn = (step < SS - 1) ? gxp[snext * G4 + t] : 0.0f;

        float acc = gxv;
        #pragma unroll
        for (int kk = 0; kk < HID / 4; kk++) {
            float4 hv = *(const float4*)&h[4 * kk];
            acc += hv.x * w[4 * kk + 0] + hv.y * w[4 * kk + 1]
                 + hv.z * w[4 * kk + 2] + hv.w * w[4 * kk + 3];
        }
        gates[t] = acc;
        __syncthreads();

        if (t < HID) {
            float ig = sigm_f(gates[t]);
            float fg = sigm_f(gates[t + HID]);
            float gg = tanh_f(gates[t + 2 * HID]);
            float og = sigm_f(gates[t + 3 * HID]);
            c = fg * c + ig * gg;
            float hh = og * tanh_f(c);
            h[t] = hh;
            outp[(size_t)s * (2 * HID) + t] = hh;
        }
        __syncthreads();

        gxv = gxn;
        s = snext;
    }
}

extern "C" void kernel_launch(void* const* d_in, const int* in_sizes, int n_in,
                              void* d_out, int out_size, void* d_ws, size_t ws_size,
                              hipStream_t stream) {
    const int* char_features      = (const int*)d_in[0];
    const int* bichar_left        = (const int*)d_in[1];
    const int* bichar_right       = (const int*)d_in[2];
    const int* static_char        = (const int*)d_in[3];
    const int* static_bichar_left = (const int*)d_in[4];
    const int* static_bichar_right= (const int*)d_in[5];
    const float* char_emb         = (const float*)d_in[6];
    const float* bichar_emb       = (const float*)d_in[7];
    const float* static_char_emb  = (const float*)d_in[8];
    const float* static_bichar_emb= (const float*)d_in[9];
    const float* W_lin            = (const float*)d_in[10];
    const float* b_lin            = (const float*)d_in[11];
    const float* Wih_l            = (const float*)d_in[12];
    const float* Whh_l            = (const float*)d_in[13];
    const float* bih_l            = (const float*)d_in[14];
    const float* bhh_l            = (const float*)d_in[15];
    const float* Wih_r            = (const float*)d_in[16];
    const float* Whh_r            = (const float*)d_in[17];
    const float* bih_r            = (const float*)d_in[18];
    const float* bhh_r            = (const float*)d_in[19];

    float* ws    = (float*)d_ws;
    float* wtlin = ws + OFF_WTLIN;
    float* wtih  = ws + OFF_WTIH;
    float* whht  = ws + OFF_WHHT;
    float* xbuf  = ws + OFF_X;
    float* gxbuf = ws + OFF_GX;
    float* out   = (float*)d_out;

    kt_wlin<<<(D_RNN * D_IN + 255) / 256, 256, 0, stream>>>(W_lin, wtlin);
    kt_wih<<<(2 * G4 * D_RNN + 255) / 256, 256, 0, stream>>>(Wih_l, Wih_r, wtih);
    kt_whh<<<(2 * G4 * HID + 255) / 256, 256, 0, stream>>>(Whh_l, Whh_r, whht);

    k_embed_linear<<<(BB * SS) / 16, 512, 0, stream>>>(
        char_features, bichar_left, bichar_right, static_char,
        static_bichar_left, static_bichar_right,
        char_emb, bichar_emb, static_char_emb, static_bichar_emb,
        wtlin, b_lin, xbuf);

    k_gatex<<<(2 * BB * SS) / 32, 512, 0, stream>>>(
        xbuf, wtih, bih_l, bhh_l, bih_r, bhh_r, gxbuf);

    k_lstm<<<2 * BB, 1024, 0, stream>>>(whht, gxbuf, out);
}